// Round 8
// baseline (253.021 us; speedup 1.0000x reference)
//
#include <hip/hip_runtime.h>
#include <hip/hip_bf16.h>

#define NEG_SLOPE 0.2f

typedef __attribute__((ext_vector_type(8))) short short8v;
typedef __attribute__((ext_vector_type(4))) float f32x4;

// ---------- bf16 round-to-nearest helpers ----------
__device__ __forceinline__ unsigned short f2bf(float f) {
    unsigned u = __float_as_uint(f);
    unsigned r = (u + 0x7FFFu + ((u >> 16) & 1u)) >> 16;
    return (unsigned short)r;
}
__device__ __forceinline__ float bf2f(unsigned short h) {
    return __uint_as_float((unsigned)h << 16);
}

// ---------- prep: zero counts + split/transpose both weights (one launch) ----------
// W1[128,256] -> w1t hi/lo [256,128]; W2[256,64] -> w2t hi/lo [64,256]
__global__ __launch_bounds__(256) void prep_kernel(int* __restrict__ counts, int N,
                                                   const float* __restrict__ W1,
                                                   unsigned short* __restrict__ h1,
                                                   unsigned short* __restrict__ l1,
                                                   const float* __restrict__ W2,
                                                   unsigned short* __restrict__ h2,
                                                   unsigned short* __restrict__ l2) {
    int tid = blockIdx.x * 256 + threadIdx.x;
    if (tid < N) { counts[tid] = 0; return; }
    tid -= N;
    if (tid < 128 * 256) {
        int k = tid >> 8, n = tid & 255;
        float f = W1[tid];
        unsigned short h = f2bf(f);
        h1[n * 128 + k] = h;
        l1[n * 128 + k] = f2bf(f - bf2f(h));
        return;
    }
    tid -= 128 * 256;
    if (tid < 256 * 64) {
        int k = tid >> 6, n = tid & 63;
        float f = W2[tid];
        unsigned short h = f2bf(f);
        h2[n * 256 + k] = h;
        l2[n * 256 + k] = f2bf(f - bf2f(h));
    }
}

// ---------- CSR build ----------
__global__ __launch_bounds__(256) void hist_kernel(const int* __restrict__ dst,
                                                   int* __restrict__ counts, int E) {
    int e = blockIdx.x * 256 + threadIdx.x;
    if (e < E) atomicAdd(counts + dst[e], 1);
}

__global__ __launch_bounds__(256) void bsum_kernel(const int* __restrict__ counts,
                                                   int* __restrict__ bsum, int N) {
    __shared__ int sh[256];
    int i = blockIdx.x * 256 + threadIdx.x;
    int v = (i < N) ? counts[i] : 0;
    sh[threadIdx.x] = v;
    __syncthreads();
    for (int off = 128; off > 0; off >>= 1) {
        if (threadIdx.x < off) sh[threadIdx.x] += sh[threadIdx.x + off];
        __syncthreads();
    }
    if (threadIdx.x == 0) bsum[blockIdx.x] = sh[0];
}

__global__ __launch_bounds__(256) void bscan_kernel(int* __restrict__ bsum, int nb,
                                                    int* __restrict__ rowptr, int N, int E) {
    __shared__ int sh[256];
    int tid = threadIdx.x;
    int carry = 0;
    for (int base = 0; base < nb; base += 256) {
        int i = base + tid;
        int v = (i < nb) ? bsum[i] : 0;
        sh[tid] = v;
        __syncthreads();
        for (int off = 1; off < 256; off <<= 1) {
            int t = (tid >= off) ? sh[tid - off] : 0;
            __syncthreads();
            sh[tid] += t;
            __syncthreads();
        }
        if (i < nb) bsum[i] = carry + sh[tid] - v;  // exclusive
        int tot = sh[255];
        __syncthreads();
        carry += tot;
    }
    if (tid == 0) rowptr[N] = E;
}

// rowptr + cursor init (cursor starts at rowptr; fill atomically bumps it)
__global__ __launch_bounds__(256) void rowptr_kernel(const int* __restrict__ counts,
                                                     const int* __restrict__ bsum,
                                                     int* __restrict__ rowptr,
                                                     int* __restrict__ cursor, int N) {
    __shared__ int sh[256];
    int i = blockIdx.x * 256 + threadIdx.x;
    int tid = threadIdx.x;
    int v = (i < N) ? counts[i] : 0;
    sh[tid] = v;
    __syncthreads();
    for (int off = 1; off < 256; off <<= 1) {
        int t = (tid >= off) ? sh[tid - off] : 0;
        __syncthreads();
        sh[tid] += t;
        __syncthreads();
    }
    if (i < N) {
        int rp = bsum[blockIdx.x] + sh[tid] - v;  // exclusive
        rowptr[i] = rp;
        cursor[i] = rp;
    }
}

__global__ __launch_bounds__(256) void fill_kernel(const int* __restrict__ src,
                                                   const int* __restrict__ dst,
                                                   int* __restrict__ cursor,
                                                   int* __restrict__ csr_src, int E) {
    int e = blockIdx.x * 256 + threadIdx.x;
    if (e >= E) return;
    int pos = atomicAdd(cursor + dst[e], 1);   // absolute position
    csr_src[pos] = src[e];
}

// ---------- MFMA GEMM with fused el/er epilogue ----------
// C[M,Nn](bf16) = A[M,K](bf16) @ Wt[Nn,K]^T  via B hi/lo x2 MFMA.
// BM=64, BN=64, BK=128; 256 thr = 4 waves; wave w -> rows w*16..+15.
// A block's 64 cols == one head (blockIdx.y); epilogue computes
// el[r*H+head] = sum_c feat*attn_l, er likewise (fp32 acc precision).
template<bool A_FP32>
__global__ __launch_bounds__(256) void gemm_mfma(const void* __restrict__ A_any,
                                                 const unsigned short* __restrict__ Bh_g,
                                                 const unsigned short* __restrict__ Bl_g,
                                                 unsigned short* __restrict__ C,
                                                 const float* __restrict__ attn_l,
                                                 const float* __restrict__ attn_r,
                                                 float* __restrict__ el,
                                                 float* __restrict__ er,
                                                 int H, int M, int Nn, int K) {
    __shared__ unsigned short Ah[64][136], Bh[64][136], Bl[64][136];
    int tid = threadIdx.x;
    int row0 = blockIdx.x * 64;
    int col0 = blockIdx.y * 64;
    int wv = tid >> 6;
    int lane = tid & 63;
    int l15 = lane & 15;
    int kgrp = (lane >> 4) * 8;

    f32x4 acc[4] = {{0.f,0.f,0.f,0.f},{0.f,0.f,0.f,0.f},{0.f,0.f,0.f,0.f},{0.f,0.f,0.f,0.f}};

    for (int kc = 0; kc < K; kc += 128) {
        __syncthreads();
        #pragma unroll
        for (int p = 0; p < 4; p++) {
            int idx = (p * 256 + tid) * 8;
            int r = idx >> 7;          // /128
            int c = idx & 127;
            int gr = row0 + r;
            if (A_FP32) {
                const float* A = (const float*)A_any;
                float4 v0 = {0,0,0,0}, v1 = {0,0,0,0};
                if (gr < M) {
                    v0 = *(const float4*)(A + (size_t)gr * K + kc + c);
                    v1 = *(const float4*)(A + (size_t)gr * K + kc + c + 4);
                }
                ushort4 h0, h1;
                h0.x = f2bf(v0.x); h0.y = f2bf(v0.y);
                h0.z = f2bf(v0.z); h0.w = f2bf(v0.w);
                h1.x = f2bf(v1.x); h1.y = f2bf(v1.y);
                h1.z = f2bf(v1.z); h1.w = f2bf(v1.w);
                *(ushort4*)&Ah[r][c]     = h0;
                *(ushort4*)&Ah[r][c + 4] = h1;
            } else {
                const unsigned short* Ah_g = (const unsigned short*)A_any;
                uint4 vh = {0,0,0,0};
                if (gr < M) vh = *(const uint4*)(Ah_g + (size_t)gr * K + kc + c);
                *(uint4*)&Ah[r][c] = vh;
            }
            // B tile: rows are output cols (Wt layout [Nn][K])
            uint4 wh = *(const uint4*)(Bh_g + (size_t)(col0 + r) * K + kc + c);
            uint4 wl = *(const uint4*)(Bl_g + (size_t)(col0 + r) * K + kc + c);
            *(uint4*)&Bh[r][c] = wh;
            *(uint4*)&Bl[r][c] = wl;
        }
        __syncthreads();
        #pragma unroll
        for (int kk = 0; kk < 4; kk++) {
            int kc0 = kk * 32 + kgrp;
            short8v ah = *(short8v*)&Ah[wv * 16 + l15][kc0];
            #pragma unroll
            for (int c = 0; c < 4; c++) {
                short8v bh = *(short8v*)&Bh[c * 16 + l15][kc0];
                short8v bl = *(short8v*)&Bl[c * 16 + l15][kc0];
                acc[c] = __builtin_amdgcn_mfma_f32_16x16x32_bf16(ah, bh, acc[c], 0, 0, 0);
                acc[c] = __builtin_amdgcn_mfma_f32_16x16x32_bf16(ah, bl, acc[c], 0, 0, 0);
            }
        }
    }
    // C/D layout: col = lane&15, row = (lane>>4)*4 + j
    float elp[4] = {0.f, 0.f, 0.f, 0.f};
    float erp[4] = {0.f, 0.f, 0.f, 0.f};
    const float* alh = attn_l + blockIdx.y * 64;
    const float* arh = attn_r + blockIdx.y * 64;
    #pragma unroll
    for (int c = 0; c < 4; c++) {
        float av = alh[c * 16 + l15];
        float rv = arh[c * 16 + l15];
        #pragma unroll
        for (int j = 0; j < 4; j++) {
            int r = row0 + wv * 16 + (lane >> 4) * 4 + j;
            if (r < M) C[(size_t)r * Nn + col0 + c * 16 + l15] = f2bf(acc[c][j]);
            elp[j] += acc[c][j] * av;
            erp[j] += acc[c][j] * rv;
        }
    }
    #pragma unroll
    for (int j = 0; j < 4; j++) {
        #pragma unroll
        for (int off = 1; off < 16; off <<= 1) {
            elp[j] += __shfl_xor(elp[j], off);
            erp[j] += __shfl_xor(erp[j], off);
        }
    }
    if (l15 == 0) {
        #pragma unroll
        for (int j = 0; j < 4; j++) {
            int r = row0 + wv * 16 + (lane >> 4) * 4 + j;
            if (r < M) {
                el[(size_t)r * H + blockIdx.y] = elp[j];
                er[(size_t)r * H + blockIdx.y] = erp[j];
            }
        }
    }
}

// ---------- layer1 fused per-node: predicated unroll x8, single-pass softmax ----------
// one wave per node; bf16 feat gather; out = bf16 (GEMM2 A operand)
__global__ __launch_bounds__(256) void gat1_node(const unsigned short* __restrict__ feat,
                                                 const float* __restrict__ el,
                                                 const float* __restrict__ er,
                                                 const int* __restrict__ rowptr,
                                                 const int* __restrict__ csr_src,
                                                 const float* __restrict__ bias,
                                                 unsigned short* __restrict__ out_h, int N) {
    int node = (blockIdx.x * 256 + threadIdx.x) >> 6;
    int lane = threadIdx.x & 63;
    if (node >= N) return;
    int h = lane >> 4;
    int beg = rowptr[node], end = rowptr[node + 1];
    float erd = er[(size_t)node * 4 + h];
    float den = 0.f;
    float4 acc = {0.f, 0.f, 0.f, 0.f};
    for (int k = beg; k < end; k += 8) {
        int s[8];
        #pragma unroll
        for (int u = 0; u < 8; u++) {
            int kk = k + u;
            s[u] = csr_src[kk < end ? kk : beg];   // clamped: always a valid load
        }
        float e[8];
        #pragma unroll
        for (int u = 0; u < 8; u++) e[u] = el[(size_t)s[u] * 4 + h];
        ushort4 f[8];
        #pragma unroll
        for (int u = 0; u < 8; u++)
            f[u] = *(const ushort4*)(feat + (size_t)s[u] * 256 + lane * 4);
        #pragma unroll
        for (int u = 0; u < 8; u++) {
            float sc = e[u] + erd;
            sc = sc > 0.f ? sc : NEG_SLOPE * sc;
            float w = (k + u < end) ? __expf(sc) : 0.f;
            den += w;
            acc.x += w * bf2f(f[u].x);
            acc.y += w * bf2f(f[u].y);
            acc.z += w * bf2f(f[u].z);
            acc.w += w * bf2f(f[u].w);
        }
    }
    float inv = (den > 0.f) ? 1.f / den : 0.f;
    float4 b = *(const float4*)(bias + lane * 4);
    ushort4 oh;
    oh.x = f2bf(fmaxf(acc.x * inv + b.x, 0.f));
    oh.y = f2bf(fmaxf(acc.y * inv + b.y, 0.f));
    oh.z = f2bf(fmaxf(acc.z * inv + b.z, 0.f));
    oh.w = f2bf(fmaxf(acc.w * inv + b.w, 0.f));
    *(ushort4*)(out_h + (size_t)node * 256 + lane * 4) = oh;
}

// ---------- layer2 fused per-node: predicated unroll x8 + bias + relu + row-sum ----------
__global__ __launch_bounds__(256) void gat2_node(const unsigned short* __restrict__ feat,
                                                 const float* __restrict__ el,
                                                 const float* __restrict__ er,
                                                 const int* __restrict__ rowptr,
                                                 const int* __restrict__ csr_src,
                                                 const float* __restrict__ bias,
                                                 float* __restrict__ emb,
                                                 float* __restrict__ go, int N) {
    int node = (blockIdx.x * 256 + threadIdx.x) >> 6;
    int lane = threadIdx.x & 63;
    if (node >= N) return;
    int beg = rowptr[node], end = rowptr[node + 1];
    float erd = er[node];
    float den = 0.f, acc = 0.f;
    for (int k = beg; k < end; k += 8) {
        int s[8];
        #pragma unroll
        for (int u = 0; u < 8; u++) {
            int kk = k + u;
            s[u] = csr_src[kk < end ? kk : beg];
        }
        float e[8];
        #pragma unroll
        for (int u = 0; u < 8; u++) e[u] = el[s[u]];
        unsigned short f[8];
        #pragma unroll
        for (int u = 0; u < 8; u++) f[u] = feat[(size_t)s[u] * 64 + lane];
        #pragma unroll
        for (int u = 0; u < 8; u++) {
            float sc = e[u] + erd;
            sc = sc > 0.f ? sc : NEG_SLOPE * sc;
            float w = (k + u < end) ? __expf(sc) : 0.f;
            den += w;
            acc += w * bf2f(f[u]);
        }
    }
    float inv = (den > 0.f) ? 1.f / den : 0.f;
    float v = fmaxf(acc * inv + bias[lane], 0.f);
    go[(size_t)node * 64 + lane] = v;
    float sum = v;
    #pragma unroll
    for (int off = 1; off < 64; off <<= 1) sum += __shfl_xor(sum, off);
    if (lane == 0) emb[node] = sum;
}

extern "C" void kernel_launch(void* const* d_in, const int* in_sizes, int n_in,
                              void* d_out, int out_size, void* d_ws, size_t ws_size,
                              hipStream_t stream) {
    const float* x   = (const float*)d_in[0];
    const int*   src = (const int*)d_in[1];
    const int*   dst = (const int*)d_in[2];
    const float* W1  = (const float*)d_in[3];
    const float* al1 = (const float*)d_in[4];
    const float* ar1 = (const float*)d_in[5];
    const float* b1  = (const float*)d_in[6];
    const float* W2  = (const float*)d_in[7];
    const float* al2 = (const float*)d_in[8];
    const float* ar2 = (const float*)d_in[9];
    const float* b2  = (const float*)d_in[10];
    const int N = in_sizes[0] / 128;
    const int E = in_sizes[1];
    const int NB = (N + 255) / 256;

    char* base = (char*)d_ws;
    size_t off = 0;
    auto alloc = [&](size_t bytes) {
        off = (off + 255) & ~(size_t)255;
        void* p = base + off;
        off += bytes;
        return p;
    };
    unsigned short* feat1 = (unsigned short*)alloc((size_t)N * 256 * 2);
    unsigned short* feat2 = (unsigned short*)alloc((size_t)N * 64 * 2);
    float* el1   = (float*)alloc((size_t)N * 4 * 4);
    float* er1   = (float*)alloc((size_t)N * 4 * 4);
    float* el2   = (float*)alloc((size_t)N * 4);
    float* er2   = (float*)alloc((size_t)N * 4);
    int* icounts = (int*)alloc((size_t)N * 4);
    int* icursor = (int*)alloc((size_t)N * 4);
    int* ibsum   = (int*)alloc((size_t)(NB + 1) * 4);
    int* irowp   = (int*)alloc((size_t)(N + 1) * 4);
    int* icsrs   = (int*)alloc((size_t)E * 4);
    unsigned short* w1th = (unsigned short*)alloc((size_t)128 * 256 * 2);
    unsigned short* w1tl = (unsigned short*)alloc((size_t)128 * 256 * 2);
    unsigned short* hh   = (unsigned short*)alloc((size_t)N * 256 * 2);
    unsigned short* w2th = (unsigned short*)alloc((size_t)256 * 64 * 2);
    unsigned short* w2tl = (unsigned short*)alloc((size_t)256 * 64 * 2);
    (void)ws_size;

    // --- prep: zero counts + split both weights ---
    {
        int tot = N + 128 * 256 + 256 * 64;
        prep_kernel<<<(tot + 255) / 256, 256, 0, stream>>>(icounts, N, W1, w1th, w1tl,
                                                           W2, w2th, w2tl);
    }

    // --- CSR build (dst-indexed) ---
    hist_kernel<<<(E + 255) / 256, 256, 0, stream>>>(dst, icounts, E);
    bsum_kernel<<<NB, 256, 0, stream>>>(icounts, ibsum, N);
    bscan_kernel<<<1, 256, 0, stream>>>(ibsum, NB, irowp, N, E);
    rowptr_kernel<<<NB, 256, 0, stream>>>(icounts, ibsum, irowp, icursor, N);
    fill_kernel<<<(E + 255) / 256, 256, 0, stream>>>(src, dst, icursor, icsrs, E);

    // --- layer 1 ---
    {
        dim3 g((N + 63) / 64, 256 / 64);
        gemm_mfma<true><<<g, 256, 0, stream>>>(x, w1th, w1tl, feat1,
                                               al1, ar1, el1, er1, 4, N, 256, 128);
    }
    gat1_node<<<(N + 3) / 4, 256, 0, stream>>>(feat1, el1, er1, irowp, icsrs, b1, hh, N);

    // --- layer 2 ---
    {
        dim3 g((N + 63) / 64, 1);
        gemm_mfma<false><<<g, 256, 0, stream>>>(hh, w2th, w2tl, feat2,
                                                al2, ar2, el2, er2, 1, N, 64, 256);
    }
    gat2_node<<<(N + 3) / 4, 256, 0, stream>>>(feat2, el2, er2, irowp, icsrs, b2,
                                               (float*)d_out, (float*)d_out + N, N);
}